// Round 8
// baseline (226.216 us; speedup 1.0000x reference)
//
#include <hip/hip_runtime.h>
#include <hip/hip_bf16.h>

#define N_NODES 100000
#define N_EDGES 1600000
#define IN_DIM 48
#define OUT_DIM 128
#define K1 144                 // 3*IN_DIM
#define NSEG (2 * N_NODES)     // 200000 segments (node x {mi,mo})
#define NMSG (2 * N_EDGES)     // 3.2M directed messages
#define NBIN 1563              // bins of 128 segments: bin = node >> 6
#define SEGPB 128              // segments per bin/block
#define BINCAP 2560            // per-bin capacity: mean 2048 + ~11 sigma
#define MAXR (BINCAP / 256)    // 10 records per thread, register-cached
#define EPB 4096               // edges per binscat block (391 blocks >= 1/CU)
#define BTHREADS 1024          // 16 waves/block -> latency hiding in binscat
#define EPT (EPB / BTHREADS)   // 4 edges per thread, register-cached
#define XROW 64                // padded xb row: 64 u16 = 128B = 1 cache line

typedef unsigned short u16;
typedef unsigned long long u64;
typedef __attribute__((ext_vector_type(8))) short short8;
typedef __attribute__((ext_vector_type(4))) float f32x4;
typedef __attribute__((ext_vector_type(4))) unsigned uint4v;

// round-to-nearest-even f32 -> bf16 bits
static __device__ __forceinline__ u16 f2bf(float f) {
  unsigned u = __float_as_uint(f);
  unsigned r = (u + 0x7fffu + ((u >> 16) & 1u)) >> 16;
  return (u16)r;
}
// fast tanh: 1 - 2/(e^{2x}+1)  (v_exp_f32 + v_rcp_f32, ~1e-6 abs error)
static __device__ __forceinline__ float ftanh(float x) {
  return 1.f - 2.f * __builtin_amdgcn_rcpf(__expf(2.f * x) + 1.f);
}

// ---------------------------------------------------------------------------
// Fragment layouts (MFMA 16x16x32 bf16, A-frag: lane l holds row (l&15),
// k-slice (l>>4)*8..+8):
//   W1f [nt(8)][ks(5)][lane(64)][8]  row nt*16+(l&15), zeros for k>=144
//   W2f [nt(8)][ks(4)][lane(64)][8]
// M semantic: k<48: mi, 48..95: mo, 96..143: x, 144..159: zero pad.
// ---------------------------------------------------------------------------

// Stage 0a: weights -> fragment order
__global__ __launch_bounds__(256) void prep_w_kernel(
    const float* __restrict__ W1, const float* __restrict__ W2,
    u16* __restrict__ W1f, u16* __restrict__ W2f)
{
  int i = blockIdx.x * 256 + threadIdx.x;
  if (i < 2560) {                       // 8 nt * 5 ks * 64 lanes
    int nt = i / 320;
    int r  = i - nt * 320;
    int ks = r >> 6, l = r & 63;
    int nrow = nt * 16 + (l & 15);
    int k0 = ks * 32 + (l >> 4) * 8;
#pragma unroll
    for (int j = 0; j < 8; ++j) {
      int k = k0 + j;
      W1f[(size_t)i * 8 + j] = (k < K1) ? f2bf(W1[nrow * K1 + k]) : (u16)0;
    }
  } else if (i < 2560 + 2048) {         // 8 nt * 4 ks * 64 lanes
    int i2 = i - 2560;
    int nt = i2 >> 8;
    int r  = i2 & 255;
    int ks = r >> 6, l = r & 63;
    int nrow = nt * 16 + (l & 15);
    int k0 = ks * 32 + (l >> 4) * 8;
#pragma unroll
    for (int j = 0; j < 8; ++j)
      W2f[(size_t)i2 * 8 + j] = f2bf(W2[nrow * OUT_DIM + k0 + j]);
  }
}

// Stage 0b: x -> padded xb rows (dims 48..63 zero -> also supplies the
// k>=144 zero pad of the MLP A-fragments).
__global__ __launch_bounds__(256) void prep_x_kernel(
    const float* __restrict__ x, u16* __restrict__ xb)
{
  int i = blockIdx.x * 256 + threadIdx.x;   // over N_NODES*64 (exact grid)
  int node = i >> 6;
  int d = i & 63;
  xb[i] = (d < IN_DIM) ? f2bf(x[node * IN_DIM + d]) : (u16)0;
}

// ---------------------------------------------------------------------------
// Phase A: binscat — partition 3.2M messages into 1563 bins (128 segs each).
// Record (8B): .x = (seg_local << 24) | src, .y = fp32 w bits.
//   dir0 (mi): dst=col -> seg even    dir1 (mo): dst=row -> seg odd
// EPB=4096 -> 391 blocks (>=1 per CU; r6's 8192/196 left 60 CUs idle).
// Only INT LDS atomics (native ds_add).
// ---------------------------------------------------------------------------
__global__ __launch_bounds__(BTHREADS) void binscat_kernel(
    const int* __restrict__ eidx, const float* __restrict__ ea,
    int* __restrict__ bin_cursor, int2* __restrict__ bkt)
{
  __shared__ int hist[NBIN];   // pass1: counts; then: within-bin write cursor
  for (int i = threadIdx.x; i < NBIN; i += BTHREADS) hist[i] = 0;
  __syncthreads();

  const int e0 = blockIdx.x * EPB;
  int rows[EPT], cols[EPT], ws[EPT];

#pragma unroll
  for (int u = 0; u < EPT; ++u) {
    int e = e0 + u * BTHREADS + threadIdx.x;
    rows[u] = -1;
    if (e < N_EDGES) {
      rows[u] = eidx[e];
      cols[u] = eidx[N_EDGES + e];
      ws[u]   = __float_as_int(ea[e]);
      atomicAdd(&hist[cols[u] >> 6], 1);
      atomicAdd(&hist[rows[u] >> 6], 1);
    }
  }
  __syncthreads();

  for (int b = threadIdx.x; b < NBIN; b += BTHREADS) {
    int c = hist[b];
    hist[b] = c ? atomicAdd(&bin_cursor[b], c) : 0;
  }
  __syncthreads();

#pragma unroll
  for (int u = 0; u < EPT; ++u) {
    if (rows[u] >= 0) {
      int row = rows[u], col = cols[u], w = ws[u];
      int seg0 = col * 2;          // mi segment (even), src = row
      int seg1 = row * 2 + 1;      // mo segment (odd),  src = col
      int s0 = atomicAdd(&hist[seg0 >> 7], 1);
      if (s0 < BINCAP)
        bkt[(size_t)(seg0 >> 7) * BINCAP + s0] =
            make_int2(((seg0 & 127) << 24) | row, w);
      int s1 = atomicAdd(&hist[seg1 >> 7], 1);
      if (s1 < BINCAP)
        bkt[(size_t)(seg1 >> 7) * BINCAP + s1] =
            make_int2(((seg1 & 127) << 24) | col, w);
    }
  }
}

// ---------------------------------------------------------------------------
// binfuse v3: one block = one bin = 128 segments = 64 nodes = 4 M-tiles.
// No float LDS atomics. Changes vs v2: records register-cached (single
// coalesced bkt pass), scan in place, srec/hsh LDS union -> 23.5KB ->
// 6 blocks/CU (24 waves) for better random-read latency hiding.
//  1. reg-cache + hist (int atomics) + in-place scan + scatter -> srec
//     (4B packed: src<<15 | w_bf15; ea>=0 so bf16 sign bit is 0).
//  2. register gather: each wave owns 32 segments, 4 rounds x 8 segments
//     (8 lanes/seg, lane r8 owns dims [8*r8,8*r8+8)). Records broadcast-
//     read from srec, rows from xb4 (one dwordx4/lane), fp32 register
//     accumulation; flush -> Msh bf16 A-fragments (disjoint writes).
//  3. MLP (verified r4-r7): per tile, layer1 MFMA from Msh(ks0-2)+xb(ks3-4)
//     + W1f -> tanh -> hsh; layer2 MFMA + W2f -> tanh -> out.
// ---------------------------------------------------------------------------
__global__ __launch_bounds__(256, 6) void binfuse_kernel(
    const int2* __restrict__ bkt, const int* __restrict__ bin_cursor,
    const uint4v* __restrict__ xb4, const u16* __restrict__ xb,
    const u16* __restrict__ W1f, const float* __restrict__ b1,
    const u16* __restrict__ W2f, const float* __restrict__ b2,
    float* __restrict__ out)
{
  // pool: phase 1-2 = srec[BINCAP] (10,240B); phase 3 = hsh[16][136] (4,352B)
  __shared__ __align__(16) char pool[BINCAP * 4];
  __shared__ __align__(16) u16 Msh[4 * 3 * 64 * 8];  // 12,288 B A-frags ks0..2
  __shared__ int offs_sh[SEGPB];                     // hist -> inclusive scan
  __shared__ int cursor[SEGPB];
  unsigned* srec = (unsigned*)pool;
  u16 (*hsh)[136] = (u16(*)[136])pool;

  const int b   = blockIdx.x;
  const int tid = threadIdx.x;
  const int cnt = min(bin_cursor[b], BINCAP);
  const int2* recs = bkt + (size_t)b * BINCAP;

  // ---- phase 1: reg-cache records, hist, in-place scan, scatter
  if (tid < SEGPB) offs_sh[tid] = 0;
  if (tid == SEGPB) srec[0] = 0;        // safe record if bin is empty
  __syncthreads();

  int2 rr[MAXR];
#pragma unroll
  for (int u = 0; u < MAXR; ++u) {
    int j = tid + u * 256;
    rr[u].x = -1;
    if (j < cnt) {
      rr[u] = recs[j];
      atomicAdd(&offs_sh[(unsigned)rr[u].x >> 24], 1);
    }
  }
  __syncthreads();

#pragma unroll
  for (int off = 1; off < SEGPB; off <<= 1) {
    int v = (tid < SEGPB && tid >= off) ? offs_sh[tid - off] : 0;
    __syncthreads();
    if (tid < SEGPB) offs_sh[tid] += v;
    __syncthreads();
  }
  if (tid < SEGPB) cursor[tid] = tid ? offs_sh[tid - 1] : 0;   // exclusive
  __syncthreads();

#pragma unroll
  for (int u = 0; u < MAXR; ++u) {
    if (rr[u].x >= 0) {
      int sl = (unsigned)rr[u].x >> 24;
      unsigned src = (unsigned)rr[u].x & 0xFFFFFFu;
      unsigned wb = f2bf(__int_as_float(rr[u].y));
      int slot = atomicAdd(&cursor[sl], 1);
      srec[slot] = (src << 15) | (wb & 0x7FFFu);
    }
  }
  __syncthreads();

  // ---- phase 2: register gather, 4 rounds x 8 segments per wave
  const int wave = tid >> 6;
  const int lane = tid & 63;
  const int g    = lane >> 3;            // segment group 0..7
  const int r8   = lane & 7;             // dim block within row

#pragma unroll
  for (int r = 0; r < 4; ++r) {
    const int sl  = wave * 32 + r * 8 + g;
    const int beg = sl ? offs_sh[sl - 1] : 0;
    const int n   = offs_sh[sl] - beg;

    int kmax = n;
    kmax = max(kmax, __shfl_xor(kmax, 8, 64));
    kmax = max(kmax, __shfl_xor(kmax, 16, 64));
    kmax = max(kmax, __shfl_xor(kmax, 32, 64));

    float a[8];
#pragma unroll
    for (int c = 0; c < 8; ++c) a[c] = 0.f;

    for (int it = 0; it < kmax; it += 2) {
      const bool p = (it     < n);
      const bool q = (it + 1 < n);
      unsigned rp = srec[p ? beg + it     : 0];   // 8-lane LDS broadcast
      unsigned rq = srec[q ? beg + it + 1 : 0];
      float wp = p ? __uint_as_float((rp & 0x7FFFu) << 16) : 0.f;
      float wq = q ? __uint_as_float((rq & 0x7FFFu) << 16) : 0.f;
      uint4v vp = xb4[(size_t)(rp >> 15) * 8 + r8];
      uint4v vq = xb4[(size_t)(rq >> 15) * 8 + r8];
#pragma unroll
      for (int c = 0; c < 4; ++c) {
        a[2 * c]     = fmaf(__uint_as_float(vp[c] << 16),         wp, a[2 * c]);
        a[2 * c + 1] = fmaf(__uint_as_float(vp[c] & 0xFFFF0000u), wp, a[2 * c + 1]);
      }
#pragma unroll
      for (int c = 0; c < 4; ++c) {
        a[2 * c]     = fmaf(__uint_as_float(vq[c] << 16),         wq, a[2 * c]);
        a[2 * c + 1] = fmaf(__uint_as_float(vq[c] & 0xFFFF0000u), wq, a[2 * c + 1]);
      }
    }

    if (r8 < 6) {                        // dims >=48 don't exist
      unsigned d[4];
#pragma unroll
      for (int c = 0; c < 4; ++c)
        d[c] = (unsigned)f2bf(a[2 * c]) | ((unsigned)f2bf(a[2 * c + 1]) << 16);
      uint4v o = {d[0], d[1], d[2], d[3]};
      const int node_l = sl >> 1;        // 0..63
      const int half   = sl & 1;         // 0: mi, 1: mo
      const int t      = node_l >> 4;
      const int nl     = node_l & 15;
      const int k0     = half * 48 + r8 * 8;
      const int ks     = k0 >> 5;        // 0..2
      const int qq     = (k0 >> 3) & 3;
      *(uint4v*)&Msh[(((t * 3 + ks) * 64) + qq * 16 + nl) * 8] = o;
    }
  }
  __syncthreads();   // srec reads done -> pool may become hsh

  // ---- phase 3: MLP over the bin's 4 tiles (block-uniform break on tail)
  const int col  = lane & 15;
  const int quad = lane >> 4;
  const int nt0  = wave * 2;

#pragma unroll 1
  for (int t = 0; t < 4; ++t) {
    const int nodeBase = b * 64 + t * 16;
    if (nodeBase >= N_NODES) break;      // uniform across block

    f32x4 acc[2];
    acc[0] = (f32x4){0.f, 0.f, 0.f, 0.f};
    acc[1] = (f32x4){0.f, 0.f, 0.f, 0.f};

#pragma unroll
    for (int ks = 0; ks < 5; ++ks) {
      short8 afr;
      if (ks < 3) {
        afr = *(const short8*)&Msh[(((t * 3 + ks) * 64) + lane) * 8];
      } else {
        const int k0 = ks * 32 + quad * 8;
        const int xc = (k0 - 96) >> 3;
        afr = *(const short8*)(xb + (size_t)(nodeBase + col) * XROW + xc * 8);
      }
#pragma unroll
      for (int ntl = 0; ntl < 2; ++ntl) {
        const int nt = nt0 + ntl;
        short8 bb = *(const short8*)(W1f + ((nt * 5 + ks) * 64 + lane) * 8);
        acc[ntl] = __builtin_amdgcn_mfma_f32_16x16x32_bf16(afr, bb, acc[ntl], 0, 0, 0);
      }
    }

#pragma unroll
    for (int ntl = 0; ntl < 2; ++ntl) {
      const int nt = nt0 + ntl;
      const int nn = nt * 16 + col;
      const float bb = b1[nn];
#pragma unroll
      for (int rg = 0; rg < 4; ++rg)
        hsh[quad * 4 + rg][nn] = f2bf(ftanh(acc[ntl][rg] + bb));
    }
    __syncthreads();

    f32x4 acc2[2];
    acc2[0] = (f32x4){0.f, 0.f, 0.f, 0.f};
    acc2[1] = (f32x4){0.f, 0.f, 0.f, 0.f};

#pragma unroll
    for (int ks = 0; ks < 4; ++ks) {
      short8 afr = *(const short8*)&hsh[col][ks * 32 + quad * 8];
#pragma unroll
      for (int ntl = 0; ntl < 2; ++ntl) {
        const int nt = nt0 + ntl;
        short8 bb = *(const short8*)(W2f + ((nt * 4 + ks) * 64 + lane) * 8);
        acc2[ntl] = __builtin_amdgcn_mfma_f32_16x16x32_bf16(afr, bb, acc2[ntl], 0, 0, 0);
      }
    }

#pragma unroll
    for (int ntl = 0; ntl < 2; ++ntl) {
      const int nt = nt0 + ntl;
      const int nn = nt * 16 + col;
      const float bb = b2[nn];
#pragma unroll
      for (int rg = 0; rg < 4; ++rg) {
        const int node = nodeBase + quad * 4 + rg;   // < N_NODES (16|N)
        out[(size_t)node * OUT_DIM + nn] = ftanh(acc2[ntl][rg] + bb);
      }
    }
    __syncthreads();                      // before hsh reuse next tile
  }
}

extern "C" void kernel_launch(void* const* d_in, const int* in_sizes, int n_in,
                              void* d_out, int out_size, void* d_ws, size_t ws_size,
                              hipStream_t stream) {
  const float* x   = (const float*)d_in[0];
  const int* eidx  = (const int*)d_in[1];
  const float* ea  = (const float*)d_in[2];
  const float* W1  = (const float*)d_in[3];
  const float* b1  = (const float*)d_in[4];
  const float* W2  = (const float*)d_in[5];
  const float* b2  = (const float*)d_in[6];
  float* out = (float*)d_out;

  // workspace layout (16B-aligned), ~45 MB total:
  char* p = (char*)d_ws;
  int2* bkt       = (int2*)p;     p += (size_t)NBIN * BINCAP * 8;      // 32.0 MB
  u16* xb         = (u16*)p;      p += (size_t)N_NODES * XROW * 2;     // 12.8 MB
  u16* W1f        = (u16*)p;      p += (size_t)2560 * 8 * 2;           // 40 KB
  u16* W2f        = (u16*)p;      p += (size_t)2048 * 8 * 2;           // 32 KB
  int* bin_cursor = (int*)p;      p += 2048 * 4;

  hipMemsetAsync(bin_cursor, 0, 2048 * 4, stream);

  prep_w_kernel<<<(2560 + 2048 + 255) / 256, 256, 0, stream>>>(W1, W2, W1f, W2f);
  prep_x_kernel<<<(N_NODES * XROW) / 256, 256, 0, stream>>>(x, xb);

  binscat_kernel<<<(N_EDGES + EPB - 1) / EPB, BTHREADS, 0, stream>>>(
      eidx, ea, bin_cursor, bkt);

  binfuse_kernel<<<NBIN, 256, 0, stream>>>(
      bkt, bin_cursor, (const uint4v*)xb, xb, W1f, b1, W2f, b2, out);
}

// Round 11
// 218.892 us; speedup vs baseline: 1.0335x; 1.0335x over previous
//
#include <hip/hip_runtime.h>
#include <hip/hip_bf16.h>

#define N_NODES 100000
#define N_EDGES 1600000
#define IN_DIM 48
#define OUT_DIM 128
#define K1 144                 // 3*IN_DIM
#define NSEG (2 * N_NODES)     // 200000 segments (node x {mi,mo})
#define NMSG (2 * N_EDGES)     // 3.2M directed messages
#define NBIN 1563              // bins of 128 segments: bin = node >> 6
#define SEGPB 128              // segments per bin/block
#define BINCAP 2560            // per-bin capacity: mean 2048 + ~11 sigma
#define MAXR (BINCAP / 256)    // 10 records per thread, register-cached
#define EPB 8192               // edges per binscat block (196 blocks; r7 vs r8
                               // A/B: 84B chunks beat 42B chunks + more blocks)
#define BTHREADS 1024
#define EPT (EPB / BTHREADS)   // 8 edges per thread, register-cached
#define XROW 64                // padded xb row: 64 u16 = 128B = 1 cache line

typedef unsigned short u16;
typedef unsigned long long u64;
typedef __attribute__((ext_vector_type(8))) short short8;
typedef __attribute__((ext_vector_type(4))) float f32x4;
typedef __attribute__((ext_vector_type(4))) unsigned uint4v;

// round-to-nearest-even f32 -> bf16 bits
static __device__ __forceinline__ u16 f2bf(float f) {
  unsigned u = __float_as_uint(f);
  unsigned r = (u + 0x7fffu + ((u >> 16) & 1u)) >> 16;
  return (u16)r;
}
// fast tanh: 1 - 2/(e^{2x}+1)  (v_exp_f32 + v_rcp_f32, ~1e-6 abs error)
static __device__ __forceinline__ float ftanh(float x) {
  return 1.f - 2.f * __builtin_amdgcn_rcpf(__expf(2.f * x) + 1.f);
}

// ---------------------------------------------------------------------------
// Fragment layouts (MFMA 16x16x32 bf16, A-frag: lane l holds row (l&15),
// k-slice (l>>4)*8..+8):
//   W1f [nt(8)][ks(5)][lane(64)][8]  row nt*16+(l&15), zeros for k>=144
//   W2f [nt(8)][ks(4)][lane(64)][8]
// M semantic: k<48: mi, 48..95: mo, 96..143: x, 144..159: zero pad.
// (Split kernels restored — r9/r10's role-merged megaprep failed the
//  container twice; reverted to the r6/r7-verified launch shapes.)
// ---------------------------------------------------------------------------

// Stage 0a: weights -> fragment order (r7-verified)
__global__ __launch_bounds__(256) void prep_w_kernel(
    const float* __restrict__ W1, const float* __restrict__ W2,
    u16* __restrict__ W1f, u16* __restrict__ W2f)
{
  int i = blockIdx.x * 256 + threadIdx.x;
  if (i < 2560) {                       // 8 nt * 5 ks * 64 lanes
    int nt = i / 320;
    int r  = i - nt * 320;
    int ks = r >> 6, l = r & 63;
    int nrow = nt * 16 + (l & 15);
    int k0 = ks * 32 + (l >> 4) * 8;
#pragma unroll
    for (int j = 0; j < 8; ++j) {
      int k = k0 + j;
      W1f[(size_t)i * 8 + j] = (k < K1) ? f2bf(W1[nrow * K1 + k]) : (u16)0;
    }
  } else if (i < 2560 + 2048) {         // 8 nt * 4 ks * 64 lanes
    int i2 = i - 2560;
    int nt = i2 >> 8;
    int r  = i2 & 255;
    int ks = r >> 6, l = r & 63;
    int nrow = nt * 16 + (l & 15);
    int k0 = ks * 32 + (l >> 4) * 8;
#pragma unroll
    for (int j = 0; j < 8; ++j)
      W2f[(size_t)i2 * 8 + j] = f2bf(W2[nrow * OUT_DIM + k0 + j]);
  }
}

// Stage 0b: x -> padded bf16 xb rows (r7-verified; pad supplies the k>=144
// zeros of the MLP A-fragments).
__global__ __launch_bounds__(256) void prep_x_kernel(
    const float* __restrict__ x, u16* __restrict__ xb)
{
  int i = blockIdx.x * 256 + threadIdx.x;   // over N_NODES*64 (exact grid)
  int node = i >> 6;
  int d = i & 63;
  xb[i] = (d < IN_DIM) ? f2bf(x[node * IN_DIM + d]) : (u16)0;
}

// ---------------------------------------------------------------------------
// Phase A: binscat — partition 3.2M messages into 1563 bins (128 segs each).
// Record (8B): .x = (seg_local << 24) | src, .y = fp32 w bits.
//   dir0 (mi): dst=col -> seg even    dir1 (mo): dst=row -> seg odd
// r6-verified shape (EPB 8192, 196 blocks). Only INT LDS atomics.
// ---------------------------------------------------------------------------
__global__ __launch_bounds__(BTHREADS) void binscat_kernel(
    const int* __restrict__ eidx, const float* __restrict__ ea,
    int* __restrict__ bin_cursor, int2* __restrict__ bkt)
{
  __shared__ int hist[NBIN];   // pass1: counts; then: within-bin write cursor
  for (int i = threadIdx.x; i < NBIN; i += BTHREADS) hist[i] = 0;
  __syncthreads();

  const int e0 = blockIdx.x * EPB;
  int rows[EPT], cols[EPT], ws[EPT];

#pragma unroll
  for (int u = 0; u < EPT; ++u) {
    int e = e0 + u * BTHREADS + threadIdx.x;
    rows[u] = -1;
    if (e < N_EDGES) {
      rows[u] = eidx[e];
      cols[u] = eidx[N_EDGES + e];
      ws[u]   = __float_as_int(ea[e]);
      atomicAdd(&hist[cols[u] >> 6], 1);
      atomicAdd(&hist[rows[u] >> 6], 1);
    }
  }
  __syncthreads();

  for (int b = threadIdx.x; b < NBIN; b += BTHREADS) {
    int c = hist[b];
    hist[b] = c ? atomicAdd(&bin_cursor[b], c) : 0;
  }
  __syncthreads();

#pragma unroll
  for (int u = 0; u < EPT; ++u) {
    if (rows[u] >= 0) {
      int row = rows[u], col = cols[u], w = ws[u];
      int seg0 = col * 2;          // mi segment (even), src = row
      int seg1 = row * 2 + 1;      // mo segment (odd),  src = col
      int s0 = atomicAdd(&hist[seg0 >> 7], 1);
      if (s0 < BINCAP)
        bkt[(size_t)(seg0 >> 7) * BINCAP + s0] =
            make_int2(((seg0 & 127) << 24) | row, w);
      int s1 = atomicAdd(&hist[seg1 >> 7], 1);
      if (s1 < BINCAP)
        bkt[(size_t)(seg1 >> 7) * BINCAP + s1] =
            make_int2(((seg1 & 127) << 24) | col, w);
    }
  }
}

// ---------------------------------------------------------------------------
// binfuse v4: one block = one bin = 128 segments = 64 nodes = 4 M-tiles.
// vs v3: phase-2 gather widened 2->4 records per iteration, all 4 record
// reads + 4 row loads issued before any FMA (2x memory-level parallelism
// per wave — r8 showed occupancy is NOT the limiter; this tests per-wave
// loads-in-flight). Per-lane accumulation order unchanged -> bit-identical.
//  1. reg-cache + hist (int atomics) + in-place scan + scatter -> srec
//  2. register gather: wave owns 32 segments, 4 rounds x 8 segments
//     (8 lanes/seg, lane r8 owns dims [8*r8,8*r8+8)); flush -> Msh frags.
//  3. MLP (verified): layer1 MFMA from Msh(ks0-2)+xb(ks3-4) + W1f -> tanh
//     -> hsh; layer2 MFMA + W2f -> tanh -> out.
// LDS 23.5KB -> 6 blocks/CU.
// ---------------------------------------------------------------------------
__global__ __launch_bounds__(256, 6) void binfuse_kernel(
    const int2* __restrict__ bkt, const int* __restrict__ bin_cursor,
    const uint4v* __restrict__ xb4, const u16* __restrict__ xb,
    const u16* __restrict__ W1f, const float* __restrict__ b1,
    const u16* __restrict__ W2f, const float* __restrict__ b2,
    float* __restrict__ out)
{
  // pool: phase 1-2 = srec[BINCAP] (10,240B); phase 3 = hsh[16][136] (4,352B)
  __shared__ __align__(16) char pool[BINCAP * 4];
  __shared__ __align__(16) u16 Msh[4 * 3 * 64 * 8];  // 12,288 B A-frags ks0..2
  __shared__ int offs_sh[SEGPB];                     // hist -> inclusive scan
  __shared__ int cursor[SEGPB];
  unsigned* srec = (unsigned*)pool;
  u16 (*hsh)[136] = (u16(*)[136])pool;

  const int b   = blockIdx.x;
  const int tid = threadIdx.x;
  const int cnt = min(bin_cursor[b], BINCAP);
  const int2* recs = bkt + (size_t)b * BINCAP;

  // ---- phase 1: reg-cache records, hist, in-place scan, scatter
  if (tid < SEGPB) offs_sh[tid] = 0;
  if (tid == SEGPB) srec[0] = 0;        // safe record if bin is empty
  __syncthreads();

  int2 rr[MAXR];
#pragma unroll
  for (int u = 0; u < MAXR; ++u) {
    int j = tid + u * 256;
    rr[u].x = -1;
    if (j < cnt) {
      rr[u] = recs[j];
      atomicAdd(&offs_sh[(unsigned)rr[u].x >> 24], 1);
    }
  }
  __syncthreads();

#pragma unroll
  for (int off = 1; off < SEGPB; off <<= 1) {
    int v = (tid < SEGPB && tid >= off) ? offs_sh[tid - off] : 0;
    __syncthreads();
    if (tid < SEGPB) offs_sh[tid] += v;
    __syncthreads();
  }
  if (tid < SEGPB) cursor[tid] = tid ? offs_sh[tid - 1] : 0;   // exclusive
  __syncthreads();

#pragma unroll
  for (int u = 0; u < MAXR; ++u) {
    if (rr[u].x >= 0) {
      int sl = (unsigned)rr[u].x >> 24;
      unsigned src = (unsigned)rr[u].x & 0xFFFFFFu;
      unsigned wb = f2bf(__int_as_float(rr[u].y));
      int slot = atomicAdd(&cursor[sl], 1);
      srec[slot] = (src << 15) | (wb & 0x7FFFu);
    }
  }
  __syncthreads();

  // ---- phase 2: register gather, 4 rounds x 8 segments per wave, 4-wide
  const int wave = tid >> 6;
  const int lane = tid & 63;
  const int g    = lane >> 3;            // segment group 0..7
  const int r8   = lane & 7;             // dim block within row

#pragma unroll
  for (int r = 0; r < 4; ++r) {
    const int sl  = wave * 32 + r * 8 + g;
    const int beg = sl ? offs_sh[sl - 1] : 0;
    const int n   = offs_sh[sl] - beg;

    int kmax = n;
    kmax = max(kmax, __shfl_xor(kmax, 8, 64));
    kmax = max(kmax, __shfl_xor(kmax, 16, 64));
    kmax = max(kmax, __shfl_xor(kmax, 32, 64));

    float a[8];
#pragma unroll
    for (int c = 0; c < 8; ++c) a[c] = 0.f;

    for (int it = 0; it < kmax; it += 4) {
      // issue all 4 record reads + 4 row loads before any FMA
      unsigned r0 = srec[(it     < n) ? beg + it     : 0];
      unsigned r1 = srec[(it + 1 < n) ? beg + it + 1 : 0];
      unsigned r2 = srec[(it + 2 < n) ? beg + it + 2 : 0];
      unsigned r3 = srec[(it + 3 < n) ? beg + it + 3 : 0];
      uint4v v0 = xb4[(size_t)(r0 >> 15) * 8 + r8];
      uint4v v1 = xb4[(size_t)(r1 >> 15) * 8 + r8];
      uint4v v2 = xb4[(size_t)(r2 >> 15) * 8 + r8];
      uint4v v3 = xb4[(size_t)(r3 >> 15) * 8 + r8];
      float w0 = (it     < n) ? __uint_as_float((r0 & 0x7FFFu) << 16) : 0.f;
      float w1 = (it + 1 < n) ? __uint_as_float((r1 & 0x7FFFu) << 16) : 0.f;
      float w2 = (it + 2 < n) ? __uint_as_float((r2 & 0x7FFFu) << 16) : 0.f;
      float w3 = (it + 3 < n) ? __uint_as_float((r3 & 0x7FFFu) << 16) : 0.f;
#pragma unroll
      for (int c = 0; c < 4; ++c) {
        a[2 * c]     = fmaf(__uint_as_float(v0[c] << 16),         w0, a[2 * c]);
        a[2 * c + 1] = fmaf(__uint_as_float(v0[c] & 0xFFFF0000u), w0, a[2 * c + 1]);
      }
#pragma unroll
      for (int c = 0; c < 4; ++c) {
        a[2 * c]     = fmaf(__uint_as_float(v1[c] << 16),         w1, a[2 * c]);
        a[2 * c + 1] = fmaf(__uint_as_float(v1[c] & 0xFFFF0000u), w1, a[2 * c + 1]);
      }
#pragma unroll
      for (int c = 0; c < 4; ++c) {
        a[2 * c]     = fmaf(__uint_as_float(v2[c] << 16),         w2, a[2 * c]);
        a[2 * c + 1] = fmaf(__uint_as_float(v2[c] & 0xFFFF0000u), w2, a[2 * c + 1]);
      }
#pragma unroll
      for (int c = 0; c < 4; ++c) {
        a[2 * c]     = fmaf(__uint_as_float(v3[c] << 16),         w3, a[2 * c]);
        a[2 * c + 1] = fmaf(__uint_as_float(v3[c] & 0xFFFF0000u), w3, a[2 * c + 1]);
      }
    }

    if (r8 < 6) {                        // dims >=48 don't exist
      unsigned d[4];
#pragma unroll
      for (int c = 0; c < 4; ++c)
        d[c] = (unsigned)f2bf(a[2 * c]) | ((unsigned)f2bf(a[2 * c + 1]) << 16);
      uint4v o = {d[0], d[1], d[2], d[3]};
      const int node_l = sl >> 1;        // 0..63
      const int half   = sl & 1;         // 0: mi, 1: mo
      const int t      = node_l >> 4;
      const int nl     = node_l & 15;
      const int k0     = half * 48 + r8 * 8;
      const int ks     = k0 >> 5;        // 0..2
      const int qq     = (k0 >> 3) & 3;
      *(uint4v*)&Msh[(((t * 3 + ks) * 64) + qq * 16 + nl) * 8] = o;
    }
  }
  __syncthreads();   // srec reads done -> pool may become hsh

  // ---- phase 3: MLP over the bin's 4 tiles (block-uniform break on tail)
  const int col  = lane & 15;
  const int quad = lane >> 4;
  const int nt0  = wave * 2;

#pragma unroll 1
  for (int t = 0; t < 4; ++t) {
    const int nodeBase = b * 64 + t * 16;
    if (nodeBase >= N_NODES) break;      // uniform across block

    f32x4 acc[2];
    acc[0] = (f32x4){0.f, 0.f, 0.f, 0.f};
    acc[1] = (f32x4){0.f, 0.f, 0.f, 0.f};

#pragma unroll
    for (int ks = 0; ks < 5; ++ks) {
      short8 afr;
      if (ks < 3) {
        afr = *(const short8*)&Msh[(((t * 3 + ks) * 64) + lane) * 8];
      } else {
        const int k0 = ks * 32 + quad * 8;
        const int xc = (k0 - 96) >> 3;
        afr = *(const short8*)(xb + (size_t)(nodeBase + col) * XROW + xc * 8);
      }
#pragma unroll
      for (int ntl = 0; ntl < 2; ++ntl) {
        const int nt = nt0 + ntl;
        short8 bb = *(const short8*)(W1f + ((nt * 5 + ks) * 64 + lane) * 8);
        acc[ntl] = __builtin_amdgcn_mfma_f32_16x16x32_bf16(afr, bb, acc[ntl], 0, 0, 0);
      }
    }

#pragma unroll
    for (int ntl = 0; ntl < 2; ++ntl) {
      const int nt = nt0 + ntl;
      const int nn = nt * 16 + col;
      const float bb = b1[nn];
#pragma unroll
      for (int rg = 0; rg < 4; ++rg)
        hsh[quad * 4 + rg][nn] = f2bf(ftanh(acc[ntl][rg] + bb));
    }
    __syncthreads();

    f32x4 acc2[2];
    acc2[0] = (f32x4){0.f, 0.f, 0.f, 0.f};
    acc2[1] = (f32x4){0.f, 0.f, 0.f, 0.f};

#pragma unroll
    for (int ks = 0; ks < 4; ++ks) {
      short8 afr = *(const short8*)&hsh[col][ks * 32 + quad * 8];
#pragma unroll
      for (int ntl = 0; ntl < 2; ++ntl) {
        const int nt = nt0 + ntl;
        short8 bb = *(const short8*)(W2f + ((nt * 4 + ks) * 64 + lane) * 8);
        acc2[ntl] = __builtin_amdgcn_mfma_f32_16x16x32_bf16(afr, bb, acc2[ntl], 0, 0, 0);
      }
    }

#pragma unroll
    for (int ntl = 0; ntl < 2; ++ntl) {
      const int nt = nt0 + ntl;
      const int nn = nt * 16 + col;
      const float bb = b2[nn];
#pragma unroll
      for (int rg = 0; rg < 4; ++rg) {
        const int node = nodeBase + quad * 4 + rg;   // < N_NODES (16|N)
        out[(size_t)node * OUT_DIM + nn] = ftanh(acc2[ntl][rg] + bb);
      }
    }
    __syncthreads();                      // before hsh reuse next tile
  }
}

extern "C" void kernel_launch(void* const* d_in, const int* in_sizes, int n_in,
                              void* d_out, int out_size, void* d_ws, size_t ws_size,
                              hipStream_t stream) {
  const float* x   = (const float*)d_in[0];
  const int* eidx  = (const int*)d_in[1];
  const float* ea  = (const float*)d_in[2];
  const float* W1  = (const float*)d_in[3];
  const float* b1  = (const float*)d_in[4];
  const float* W2  = (const float*)d_in[5];
  const float* b2  = (const float*)d_in[6];
  float* out = (float*)d_out;

  // workspace layout (16B-aligned), ~45 MB total:
  char* p = (char*)d_ws;
  int2* bkt       = (int2*)p;     p += (size_t)NBIN * BINCAP * 8;      // 32.0 MB
  u16* xb         = (u16*)p;      p += (size_t)N_NODES * XROW * 2;     // 12.8 MB
  u16* W1f        = (u16*)p;      p += (size_t)2560 * 8 * 2;           // 40 KB
  u16* W2f        = (u16*)p;      p += (size_t)2048 * 8 * 2;           // 32 KB
  int* bin_cursor = (int*)p;      p += 2048 * 4;

  hipMemsetAsync(bin_cursor, 0, 2048 * 4, stream);

  prep_w_kernel<<<(2560 + 2048 + 255) / 256, 256, 0, stream>>>(W1, W2, W1f, W2f);
  prep_x_kernel<<<(N_NODES * XROW) / 256, 256, 0, stream>>>(x, xb);

  binscat_kernel<<<(N_EDGES + EPB - 1) / EPB, BTHREADS, 0, stream>>>(
      eidx, ea, bin_cursor, bkt);

  binfuse_kernel<<<NBIN, 256, 0, stream>>>(
      bkt, bin_cursor, (const uint4v*)xb, xb, W1f, b1, W2f, b2, out);
}

// Round 12
// 212.830 us; speedup vs baseline: 1.0629x; 1.0285x over previous
//
#include <hip/hip_runtime.h>
#include <hip/hip_bf16.h>

#define N_NODES 100000
#define N_EDGES 1600000
#define IN_DIM 48
#define OUT_DIM 128
#define K1 144                 // 3*IN_DIM
#define NSEG (2 * N_NODES)     // 200000 segments (node x {mi,mo})
#define NMSG (2 * N_EDGES)     // 3.2M directed messages
#define NBIN 1563              // bins of 128 segments: bin = node >> 6
#define SEGPB 128              // segments per bin/block
#define BINCAP 2560            // per-bin capacity: mean 2048 + ~11 sigma
#define MAXR (BINCAP / 256)    // 10 records per thread, register-cached
#define EPB 8192               // edges per binscat block (196 blocks; r7 vs r8
                               // A/B: 84B chunks beat 42B chunks + more blocks)
#define BTHREADS 1024
#define EPT (EPB / BTHREADS)   // 8 edges per thread, register-cached
#define XROW 64                // padded xb row: 64 u16 = 128B = 1 cache line
#define HPAD 132               // wave-private hsh row stride (bank-spread)

typedef unsigned short u16;
typedef unsigned long long u64;
typedef __attribute__((ext_vector_type(8))) short short8;
typedef __attribute__((ext_vector_type(4))) float f32x4;
typedef __attribute__((ext_vector_type(4))) unsigned uint4v;

// round-to-nearest-even f32 -> bf16 bits
static __device__ __forceinline__ u16 f2bf(float f) {
  unsigned u = __float_as_uint(f);
  unsigned r = (u + 0x7fffu + ((u >> 16) & 1u)) >> 16;
  return (u16)r;
}
// fast tanh: 1 - 2/(e^{2x}+1)  (v_exp_f32 + v_rcp_f32, ~1e-6 abs error)
static __device__ __forceinline__ float ftanh(float x) {
  return 1.f - 2.f * __builtin_amdgcn_rcpf(__expf(2.f * x) + 1.f);
}

// ---------------------------------------------------------------------------
// Fragment layouts (MFMA 16x16x32 bf16, A-frag: lane l holds row (l&15),
// k-slice (l>>4)*8..+8):
//   W1f [nt(8)][ks(5)][lane(64)][8]  row nt*16+(l&15), zeros for k>=144
//   W2f [nt(8)][ks(4)][lane(64)][8]
// M semantic: k<48: mi, 48..95: mo, 96..143: x, 144..159: zero pad.
// ---------------------------------------------------------------------------

// Stage 0a: weights -> fragment order (r7-verified)
__global__ __launch_bounds__(256) void prep_w_kernel(
    const float* __restrict__ W1, const float* __restrict__ W2,
    u16* __restrict__ W1f, u16* __restrict__ W2f)
{
  int i = blockIdx.x * 256 + threadIdx.x;
  if (i < 2560) {                       // 8 nt * 5 ks * 64 lanes
    int nt = i / 320;
    int r  = i - nt * 320;
    int ks = r >> 6, l = r & 63;
    int nrow = nt * 16 + (l & 15);
    int k0 = ks * 32 + (l >> 4) * 8;
#pragma unroll
    for (int j = 0; j < 8; ++j) {
      int k = k0 + j;
      W1f[(size_t)i * 8 + j] = (k < K1) ? f2bf(W1[nrow * K1 + k]) : (u16)0;
    }
  } else if (i < 2560 + 2048) {         // 8 nt * 4 ks * 64 lanes
    int i2 = i - 2560;
    int nt = i2 >> 8;
    int r  = i2 & 255;
    int ks = r >> 6, l = r & 63;
    int nrow = nt * 16 + (l & 15);
    int k0 = ks * 32 + (l >> 4) * 8;
#pragma unroll
    for (int j = 0; j < 8; ++j)
      W2f[(size_t)i2 * 8 + j] = f2bf(W2[nrow * OUT_DIM + k0 + j]);
  }
}

// Stage 0b: x -> padded bf16 xb rows (r7-verified; pad supplies the k>=144
// zeros of the MLP A-fragments).
__global__ __launch_bounds__(256) void prep_x_kernel(
    const float* __restrict__ x, u16* __restrict__ xb)
{
  int i = blockIdx.x * 256 + threadIdx.x;   // over N_NODES*64 (exact grid)
  int node = i >> 6;
  int d = i & 63;
  xb[i] = (d < IN_DIM) ? f2bf(x[node * IN_DIM + d]) : (u16)0;
}

// ---------------------------------------------------------------------------
// Phase A: binscat — partition 3.2M messages into 1563 bins (128 segs each).
// Record (8B): .x = (seg_local << 24) | src, .y = fp32 w bits.
//   dir0 (mi): dst=col -> seg even    dir1 (mo): dst=row -> seg odd
// r6-verified shape (EPB 8192, 196 blocks). Only INT LDS atomics.
// ---------------------------------------------------------------------------
__global__ __launch_bounds__(BTHREADS) void binscat_kernel(
    const int* __restrict__ eidx, const float* __restrict__ ea,
    int* __restrict__ bin_cursor, int2* __restrict__ bkt)
{
  __shared__ int hist[NBIN];   // pass1: counts; then: within-bin write cursor
  for (int i = threadIdx.x; i < NBIN; i += BTHREADS) hist[i] = 0;
  __syncthreads();

  const int e0 = blockIdx.x * EPB;
  int rows[EPT], cols[EPT], ws[EPT];

#pragma unroll
  for (int u = 0; u < EPT; ++u) {
    int e = e0 + u * BTHREADS + threadIdx.x;
    rows[u] = -1;
    if (e < N_EDGES) {
      rows[u] = eidx[e];
      cols[u] = eidx[N_EDGES + e];
      ws[u]   = __float_as_int(ea[e]);
      atomicAdd(&hist[cols[u] >> 6], 1);
      atomicAdd(&hist[rows[u] >> 6], 1);
    }
  }
  __syncthreads();

  for (int b = threadIdx.x; b < NBIN; b += BTHREADS) {
    int c = hist[b];
    hist[b] = c ? atomicAdd(&bin_cursor[b], c) : 0;
  }
  __syncthreads();

#pragma unroll
  for (int u = 0; u < EPT; ++u) {
    if (rows[u] >= 0) {
      int row = rows[u], col = cols[u], w = ws[u];
      int seg0 = col * 2;          // mi segment (even), src = row
      int seg1 = row * 2 + 1;      // mo segment (odd),  src = col
      int s0 = atomicAdd(&hist[seg0 >> 7], 1);
      if (s0 < BINCAP)
        bkt[(size_t)(seg0 >> 7) * BINCAP + s0] =
            make_int2(((seg0 & 127) << 24) | row, w);
      int s1 = atomicAdd(&hist[seg1 >> 7], 1);
      if (s1 < BINCAP)
        bkt[(size_t)(seg1 >> 7) * BINCAP + s1] =
            make_int2(((seg1 & 127) << 24) | col, w);
    }
  }
}

// ---------------------------------------------------------------------------
// binfuse v5: wave-private pipeline to break phase lockstep.
// r8 (occupancy) and r11 (load width) were both null at 86us: all resident
// blocks have near-identical work, so they march through phases in lockstep
// and the CU never overlaps memory-phase waves with MFMA-phase waves.
// v5: wave w owns tile w = 16 nodes = 32 segments END TO END:
//   phase 1 (block-coop, barriers): sort bin's records into srec by segment.
//   phase 2 (wave-private): gather wave's 32 segments (4 rounds x 8 segs,
//     8 lanes/seg, 4-wide) -> Msh[wave] A-frags. No block barrier after.
//   phase 3 (wave-private): layer1 MFMA (all 8 nt) from Msh[wave]+xb -> tanh
//     -> hsh[wave] -> layer2 MFMA -> tanh -> out. Same total MFMA, remapped.
// Waves desync via kmax variance -> CU mixes memory and MFMA waves.
// LDS: srec 10,240 + Msh 12,288 + hsh 4x4,224 + tables 1,024 = 40,448
//   -> 4 blocks/CU.
// ---------------------------------------------------------------------------
__global__ __launch_bounds__(256, 4) void binfuse_kernel(
    const int2* __restrict__ bkt, const int* __restrict__ bin_cursor,
    const uint4v* __restrict__ xb4, const u16* __restrict__ xb,
    const u16* __restrict__ W1f, const float* __restrict__ b1,
    const u16* __restrict__ W2f, const float* __restrict__ b2,
    float* __restrict__ out)
{
  __shared__ unsigned srec[BINCAP];                  // 10,240 B sorted records
  __shared__ __align__(16) u16 Msh[4 * 3 * 64 * 8];  // 12,288 B A-frags ks0..2
  __shared__ __align__(16) u16 hsh[4][16][HPAD];     // 16,896 B wave-private h
  __shared__ int offs_sh[SEGPB];                     // hist -> inclusive scan
  __shared__ int cursor[SEGPB];

  const int b   = blockIdx.x;
  const int tid = threadIdx.x;
  const int cnt = min(bin_cursor[b], BINCAP);
  const int2* recs = bkt + (size_t)b * BINCAP;

  // ---- phase 1: reg-cache records, hist, in-place scan, scatter (coop)
  if (tid < SEGPB) offs_sh[tid] = 0;
  if (tid == SEGPB) srec[0] = 0;        // safe record if bin is empty
  __syncthreads();

  int2 rr[MAXR];
#pragma unroll
  for (int u = 0; u < MAXR; ++u) {
    int j = tid + u * 256;
    rr[u].x = -1;
    if (j < cnt) {
      rr[u] = recs[j];
      atomicAdd(&offs_sh[(unsigned)rr[u].x >> 24], 1);
    }
  }
  __syncthreads();

#pragma unroll
  for (int off = 1; off < SEGPB; off <<= 1) {
    int v = (tid < SEGPB && tid >= off) ? offs_sh[tid - off] : 0;
    __syncthreads();
    if (tid < SEGPB) offs_sh[tid] += v;
    __syncthreads();
  }
  if (tid < SEGPB) cursor[tid] = tid ? offs_sh[tid - 1] : 0;   // exclusive
  __syncthreads();

#pragma unroll
  for (int u = 0; u < MAXR; ++u) {
    if (rr[u].x >= 0) {
      int sl = (unsigned)rr[u].x >> 24;
      unsigned src = (unsigned)rr[u].x & 0xFFFFFFu;
      unsigned wb = f2bf(__int_as_float(rr[u].y));
      int slot = atomicAdd(&cursor[sl], 1);
      srec[slot] = (src << 15) | (wb & 0x7FFFu);
    }
  }
  __syncthreads();   // srec complete; from here each wave runs independently

  // ---- phase 2: wave-private gather, 4 rounds x 8 segments, 4-wide
  const int wave = tid >> 6;
  const int lane = tid & 63;
  const int g    = lane >> 3;            // segment group 0..7
  const int r8   = lane & 7;             // dim block within row

#pragma unroll
  for (int r = 0; r < 4; ++r) {
    const int sl  = wave * 32 + r * 8 + g;
    const int beg = sl ? offs_sh[sl - 1] : 0;
    const int n   = offs_sh[sl] - beg;

    int kmax = n;
    kmax = max(kmax, __shfl_xor(kmax, 8, 64));
    kmax = max(kmax, __shfl_xor(kmax, 16, 64));
    kmax = max(kmax, __shfl_xor(kmax, 32, 64));

    float a[8];
#pragma unroll
    for (int c = 0; c < 8; ++c) a[c] = 0.f;

    for (int it = 0; it < kmax; it += 4) {
      unsigned r0 = srec[(it     < n) ? beg + it     : 0];
      unsigned r1 = srec[(it + 1 < n) ? beg + it + 1 : 0];
      unsigned r2 = srec[(it + 2 < n) ? beg + it + 2 : 0];
      unsigned r3 = srec[(it + 3 < n) ? beg + it + 3 : 0];
      uint4v v0 = xb4[(size_t)(r0 >> 15) * 8 + r8];
      uint4v v1 = xb4[(size_t)(r1 >> 15) * 8 + r8];
      uint4v v2 = xb4[(size_t)(r2 >> 15) * 8 + r8];
      uint4v v3 = xb4[(size_t)(r3 >> 15) * 8 + r8];
      float w0 = (it     < n) ? __uint_as_float((r0 & 0x7FFFu) << 16) : 0.f;
      float w1 = (it + 1 < n) ? __uint_as_float((r1 & 0x7FFFu) << 16) : 0.f;
      float w2 = (it + 2 < n) ? __uint_as_float((r2 & 0x7FFFu) << 16) : 0.f;
      float w3 = (it + 3 < n) ? __uint_as_float((r3 & 0x7FFFu) << 16) : 0.f;
#pragma unroll
      for (int c = 0; c < 4; ++c) {
        a[2 * c]     = fmaf(__uint_as_float(v0[c] << 16),         w0, a[2 * c]);
        a[2 * c + 1] = fmaf(__uint_as_float(v0[c] & 0xFFFF0000u), w0, a[2 * c + 1]);
      }
#pragma unroll
      for (int c = 0; c < 4; ++c) {
        a[2 * c]     = fmaf(__uint_as_float(v1[c] << 16),         w1, a[2 * c]);
        a[2 * c + 1] = fmaf(__uint_as_float(v1[c] & 0xFFFF0000u), w1, a[2 * c + 1]);
      }
#pragma unroll
      for (int c = 0; c < 4; ++c) {
        a[2 * c]     = fmaf(__uint_as_float(v2[c] << 16),         w2, a[2 * c]);
        a[2 * c + 1] = fmaf(__uint_as_float(v2[c] & 0xFFFF0000u), w2, a[2 * c + 1]);
      }
#pragma unroll
      for (int c = 0; c < 4; ++c) {
        a[2 * c]     = fmaf(__uint_as_float(v3[c] << 16),         w3, a[2 * c]);
        a[2 * c + 1] = fmaf(__uint_as_float(v3[c] & 0xFFFF0000u), w3, a[2 * c + 1]);
      }
    }

    if (r8 < 6) {                        // dims >=48 don't exist
      unsigned d[4];
#pragma unroll
      for (int c = 0; c < 4; ++c)
        d[c] = (unsigned)f2bf(a[2 * c]) | ((unsigned)f2bf(a[2 * c + 1]) << 16);
      uint4v o = {d[0], d[1], d[2], d[3]};
      const int node_l = sl >> 1;        // 0..63; node_l>>4 == wave
      const int half   = sl & 1;         // 0: mi, 1: mo
      const int t      = node_l >> 4;    // == wave
      const int nl     = node_l & 15;
      const int k0     = half * 48 + r8 * 8;
      const int ks     = k0 >> 5;        // 0..2
      const int qq     = (k0 >> 3) & 3;
      *(uint4v*)&Msh[(((t * 3 + ks) * 64) + qq * 16 + nl) * 8] = o;
    }
  }
  // NO block barrier: Msh[wave] is written and read by this wave only.
  // (compiler orders the ds_write -> ds_read dependency via lgkmcnt)

  // ---- phase 3: wave-private MLP for tile = b*4 + wave
  const int col  = lane & 15;
  const int quad = lane >> 4;
  const int nodeBase = b * 64 + wave * 16;
  if (nodeBase >= N_NODES) return;       // wave-uniform (tail bin)

  f32x4 acc[8];
#pragma unroll
  for (int nt = 0; nt < 8; ++nt) acc[nt] = (f32x4){0.f, 0.f, 0.f, 0.f};

#pragma unroll
  for (int ks = 0; ks < 5; ++ks) {
    short8 afr;
    if (ks < 3) {
      afr = *(const short8*)&Msh[(((wave * 3 + ks) * 64) + lane) * 8];
    } else {
      const int k0 = ks * 32 + quad * 8;
      const int xc = (k0 - 96) >> 3;
      afr = *(const short8*)(xb + (size_t)(nodeBase + col) * XROW + xc * 8);
    }
#pragma unroll
    for (int nt = 0; nt < 8; ++nt) {
      short8 bb = *(const short8*)(W1f + ((nt * 5 + ks) * 64 + lane) * 8);
      acc[nt] = __builtin_amdgcn_mfma_f32_16x16x32_bf16(afr, bb, acc[nt], 0, 0, 0);
    }
  }

#pragma unroll
  for (int nt = 0; nt < 8; ++nt) {
    const int nn = nt * 16 + col;
    const float bb = b1[nn];
#pragma unroll
    for (int rg = 0; rg < 4; ++rg)
      hsh[wave][quad * 4 + rg][nn] = f2bf(ftanh(acc[nt][rg] + bb));
  }
  // wave-private hsh: same-wave ds_write -> ds_read, no barrier needed

  f32x4 acc2[8];
#pragma unroll
  for (int nt = 0; nt < 8; ++nt) acc2[nt] = (f32x4){0.f, 0.f, 0.f, 0.f};

#pragma unroll
  for (int ks = 0; ks < 4; ++ks) {
    short8 afr = *(const short8*)&hsh[wave][col][ks * 32 + quad * 8];
#pragma unroll
    for (int nt = 0; nt < 8; ++nt) {
      short8 bb = *(const short8*)(W2f + ((nt * 4 + ks) * 64 + lane) * 8);
      acc2[nt] = __builtin_amdgcn_mfma_f32_16x16x32_bf16(afr, bb, acc2[nt], 0, 0, 0);
    }
  }

#pragma unroll
  for (int nt = 0; nt < 8; ++nt) {
    const int nn = nt * 16 + col;
    const float bb = b2[nn];
#pragma unroll
    for (int rg = 0; rg < 4; ++rg) {
      const int node = nodeBase + quad * 4 + rg;   // < N_NODES (16|N)
      out[(size_t)node * OUT_DIM + nn] = ftanh(acc2[nt][rg] + bb);
    }
  }
}

extern "C" void kernel_launch(void* const* d_in, const int* in_sizes, int n_in,
                              void* d_out, int out_size, void* d_ws, size_t ws_size,
                              hipStream_t stream) {
  const float* x   = (const float*)d_in[0];
  const int* eidx  = (const int*)d_in[1];
  const float* ea  = (const float*)d_in[2];
  const float* W1  = (const float*)d_in[3];
  const float* b1  = (const float*)d_in[4];
  const float* W2  = (const float*)d_in[5];
  const float* b2  = (const float*)d_in[6];
  float* out = (float*)d_out;

  // workspace layout (16B-aligned), ~45 MB total:
  char* p = (char*)d_ws;
  int2* bkt       = (int2*)p;     p += (size_t)NBIN * BINCAP * 8;      // 32.0 MB
  u16* xb         = (u16*)p;      p += (size_t)N_NODES * XROW * 2;     // 12.8 MB
  u16* W1f        = (u16*)p;      p += (size_t)2560 * 8 * 2;           // 40 KB
  u16* W2f        = (u16*)p;      p += (size_t)2048 * 8 * 2;           // 32 KB
  int* bin_cursor = (int*)p;      p += 2048 * 4;

  hipMemsetAsync(bin_cursor, 0, 2048 * 4, stream);

  prep_w_kernel<<<(2560 + 2048 + 255) / 256, 256, 0, stream>>>(W1, W2, W1f, W2f);
  prep_x_kernel<<<(N_NODES * XROW) / 256, 256, 0, stream>>>(x, xb);

  binscat_kernel<<<(N_EDGES + EPB - 1) / EPB, BTHREADS, 0, stream>>>(
      eidx, ea, bin_cursor, bkt);

  binfuse_kernel<<<NBIN, 256, 0, stream>>>(
      bkt, bin_cursor, (const uint4v*)xb, xb, W1f, b1, W2f, b2, out);
}